// Round 1
// baseline (191.472 us; speedup 1.0000x reference)
//
#include <hip/hip_runtime.h>

#define BB 64
#define CC 64
#define TT 4000
#define SLABS 8
#define TSLAB (TT / SLABS)   // 500
#define TCH 100              // t-chunk staged in LDS per iteration
#define NCHUNK (TSLAB / TCH) // 5
#define NTILE ((TT + 63) / 64)  // 63 t-tiles of 64 for apply kernel

// ws layout (floats):
//   G : BB*CC*CC   (Gram; overwritten in-place by attention)
//   S : BB*CC      (row sums)
#define G_ELEMS ((size_t)BB * CC * CC)
#define S_ELEMS ((size_t)BB * CC)

__global__ __launch_bounds__(256)
void zero_ws_kernel(float* __restrict__ ws) {
    size_t n = G_ELEMS + S_ELEMS;
    size_t i = (size_t)blockIdx.x * blockDim.x + threadIdx.x;
    if (i * 4 + 3 < n) {
        *(float4*)(ws + i * 4) = make_float4(0.f, 0.f, 0.f, 0.f);
    } else {
        for (size_t k = i * 4; k < n; ++k) ws[k] = 0.f;
    }
}

// G[b][r][c] = sum_t x[b][r][t] * x[b][c][t] ; S[b][c] = sum_t x[b][c][t]
__global__ __launch_bounds__(256)
void gram_kernel(const float* __restrict__ x, float* __restrict__ G,
                 float* __restrict__ S) {
    __shared__ float xs[CC * TCH];           // 25.6 KB, pitch 100 (400B rows, 16B aligned)
    const int b    = blockIdx.x / SLABS;
    const int slab = blockIdx.x % SLABS;
    const int t0   = slab * TSLAB;
    const int tid  = threadIdx.x;
    const int tx   = tid & 15, ty = tid >> 4;
    const float* xb = x + (size_t)b * CC * TT;

    float acc[4][4] = {{0.f, 0.f, 0.f, 0.f}, {0.f, 0.f, 0.f, 0.f},
                       {0.f, 0.f, 0.f, 0.f}, {0.f, 0.f, 0.f, 0.f}};
    float rsum = 0.f;

    for (int ch = 0; ch < NCHUNK; ++ch) {
        const int tb = t0 + ch * TCH;
        __syncthreads();
        // stage 64 x 100 chunk, float4 (100 % 4 == 0 so rows stay 16B-aligned)
        for (int idx = tid; idx < CC * (TCH / 4); idx += 256) {
            int c = idx / (TCH / 4);
            int p = idx - c * (TCH / 4);
            float4 v = *(const float4*)(xb + c * TT + tb + 4 * p);
            *(float4*)(xs + c * TCH + 4 * p) = v;
        }
        __syncthreads();
        // partial row sums: thread owns (c = tid&63, quarter q = tid>>6)
        {
            int c = tid & 63, q = tid >> 6;
            const float* row = xs + c * TCH + q * (TCH / 4);
            float s = 0.f;
            #pragma unroll
            for (int j = 0; j < TCH / 4; ++j) s += row[j];
            rsum += s;
        }
        // 4x4 register tile: rows {ty+16i}, cols {tx+16j} (stride-16 split ->
        // a-reads are 4-addr broadcast, b-reads 2-way max: conflict-free)
        for (int tc = 0; tc < TCH; tc += 4) {
            float4 av[4], bv[4];
            #pragma unroll
            for (int i = 0; i < 4; ++i)
                av[i] = *(const float4*)(xs + (ty + 16 * i) * TCH + tc);
            #pragma unroll
            for (int j = 0; j < 4; ++j)
                bv[j] = *(const float4*)(xs + (tx + 16 * j) * TCH + tc);
            #pragma unroll
            for (int i = 0; i < 4; ++i)
                #pragma unroll
                for (int j = 0; j < 4; ++j)
                    acc[i][j] += av[i].x * bv[j].x + av[i].y * bv[j].y +
                                 av[i].z * bv[j].z + av[i].w * bv[j].w;
        }
    }
    atomicAdd(S + b * CC + (tid & 63), rsum);
    float* Gb = G + (size_t)b * CC * CC;
    #pragma unroll
    for (int i = 0; i < 4; ++i)
        #pragma unroll
        for (int j = 0; j < 4; ++j)
            atomicAdd(Gb + (ty + 16 * i) * CC + (tx + 16 * j), acc[i][j]);
}

// energy -> minmax-norm -> softmax; attention written in-place over G.
// One wave per (b,c) row; lane = e.
__global__ __launch_bounds__(64)
void softmax_kernel(const float* __restrict__ w1, const float* __restrict__ b1,
                    const float* __restrict__ w2, const float* __restrict__ b2,
                    float* __restrict__ G, const float* __restrict__ S) {
    const int row = blockIdx.x;      // b*64 + c
    const int b = row >> 6, c = row & 63;
    const int e = threadIdx.x;

    float A = 0.f, Bc = 0.f, Be = 0.f, Cc = 0.f;
    #pragma unroll
    for (int j = 0; j < 8; ++j) {
        float a1 = w1[j], a2 = w2[j], q1 = b1[j], q2 = b2[j];
        A  += a1 * a2;
        Bc += a1 * q2;
        Be += q1 * a2;
        Cc += q1 * q2;
    }
    Cc *= (float)TT;

    float g  = G[(size_t)row * CC + e];
    float sc = S[b * CC + c];
    float se = S[b * CC + e];
    float energy = A * g + Bc * sc + Be * se + Cc;

    float mx = energy, mn = energy;
    #pragma unroll
    for (int off = 32; off; off >>= 1) {
        mx = fmaxf(mx, __shfl_xor(mx, off, 64));
        mn = fminf(mn, __shfl_xor(mn, off, 64));
    }
    float norm = (energy - mn) / (mx - mn + 1e-8f);
    float p = __expf(norm);
    float sum = p;
    #pragma unroll
    for (int off = 32; off; off >>= 1) sum += __shfl_xor(sum, off, 64);
    G[(size_t)row * CC + e] = p / sum;
}

// out[b,c,t] = gamma * sum_e att[b,e,c] * x[b,e,t] + x[b,c,t]
__global__ __launch_bounds__(256)
void apply_kernel(const float* __restrict__ x, const float* __restrict__ att,
                  const float* __restrict__ gamma, float* __restrict__ out) {
    __shared__ float As[CC * CC];   // As[e*64+c] = att[b][e][c] (direct copy)
    __shared__ float xs[CC * 64];   // xs[e*64+tl] = x[b][e][t0+tl]
    const int b  = blockIdx.x / NTILE;
    const int t0 = (blockIdx.x % NTILE) * 64;
    const int tid = threadIdx.x;
    const int tx = tid & 15, ty = tid >> 4;
    const float* attb = att + (size_t)b * CC * CC;
    const float* xb   = x + (size_t)b * CC * TT;

    for (int idx = tid; idx < CC * CC / 4; idx += 256)
        *(float4*)(As + 4 * idx) = *(const float4*)(attb + 4 * idx);
    for (int idx = tid; idx < CC * 16; idx += 256) {
        int e = idx >> 4, p = idx & 15;
        int t = t0 + 4 * p;
        float4 v = make_float4(0.f, 0.f, 0.f, 0.f);
        if (t < TT) v = *(const float4*)(xb + e * TT + t);   // TT%4==0: all-or-none
        *(float4*)(xs + e * 64 + 4 * p) = v;
    }
    __syncthreads();

    // thread tile: c in [4ty,4ty+4), t-local in [4tx,4tx+4)
    float acc[4][4] = {{0.f, 0.f, 0.f, 0.f}, {0.f, 0.f, 0.f, 0.f},
                       {0.f, 0.f, 0.f, 0.f}, {0.f, 0.f, 0.f, 0.f}};
    for (int e = 0; e < CC; ++e) {
        float4 m = *(const float4*)(As + e * 64 + 4 * ty);  // M[c][e] for 4 c
        float4 v = *(const float4*)(xs + e * 64 + 4 * tx);  // x[e][t] for 4 t
        #pragma unroll
        for (int i = 0; i < 4; ++i) {
            float mi = (i == 0) ? m.x : (i == 1) ? m.y : (i == 2) ? m.z : m.w;
            acc[i][0] += mi * v.x;
            acc[i][1] += mi * v.y;
            acc[i][2] += mi * v.z;
            acc[i][3] += mi * v.w;
        }
    }

    const float gm = gamma[0];
    float4 res[4];
    #pragma unroll
    for (int i = 0; i < 4; ++i) {
        float4 xr = *(const float4*)(xs + (4 * ty + i) * 64 + 4 * tx);
        res[i] = make_float4(gm * acc[i][0] + xr.x, gm * acc[i][1] + xr.y,
                             gm * acc[i][2] + xr.z, gm * acc[i][3] + xr.w);
    }
    __syncthreads();
    #pragma unroll
    for (int i = 0; i < 4; ++i)
        *(float4*)(xs + (4 * ty + i) * 64 + 4 * tx) = res[i];
    __syncthreads();

    float* ob = out + (size_t)b * CC * TT;
    for (int idx = tid; idx < CC * 16; idx += 256) {
        int c = idx >> 4, p = idx & 15;
        int t = t0 + 4 * p;
        if (t < TT)
            *(float4*)(ob + c * TT + t) = *(const float4*)(xs + c * 64 + 4 * p);
    }
}

extern "C" void kernel_launch(void* const* d_in, const int* in_sizes, int n_in,
                              void* d_out, int out_size, void* d_ws, size_t ws_size,
                              hipStream_t stream) {
    const float* x  = (const float*)d_in[0];
    const float* w1 = (const float*)d_in[1];
    const float* b1 = (const float*)d_in[2];
    const float* w2 = (const float*)d_in[3];
    const float* b2 = (const float*)d_in[4];
    const float* gm = (const float*)d_in[5];
    float* out = (float*)d_out;
    float* G = (float*)d_ws;
    float* S = G + G_ELEMS;

    size_t zn = (G_ELEMS + S_ELEMS + 3) / 4;          // float4 units
    hipLaunchKernelGGL(zero_ws_kernel, dim3((zn + 255) / 256), dim3(256), 0, stream,
                       (float*)d_ws);
    hipLaunchKernelGGL(gram_kernel, dim3(BB * SLABS), dim3(256), 0, stream, x, G, S);
    hipLaunchKernelGGL(softmax_kernel, dim3(BB * CC), dim3(64), 0, stream,
                       w1, b1, w2, b2, G, S);
    hipLaunchKernelGGL(apply_kernel, dim3(BB * NTILE), dim3(256), 0, stream,
                       x, G, gm, out);
}